// Round 9
// baseline (1130.236 us; speedup 1.0000x reference)
//
#include <hip/hip_runtime.h>
#include <hip/hip_fp16.h>
#include <stdint.h>

typedef __attribute__((ext_vector_type(8))) _Float16 half8;
typedef __attribute__((ext_vector_type(2))) _Float16 half2v;
typedef __attribute__((ext_vector_type(8))) short short8;
typedef __attribute__((ext_vector_type(4))) float floatx4;
typedef __attribute__((ext_vector_type(2))) float float2v;

#define K_DIM 4096
#define N_DIM 11008
#define NQ_DIM 1376
#define NT_DIM 86
#define BK 32
#define NSTEPS 128
#define BM 128
#define BN 128

__device__ __forceinline__ uint32_t pkh(float a, float b) {
    half2v h; h[0] = (_Float16)a; h[1] = (_Float16)b;
    union { half2v h; uint32_t u; } c; c.h = h; return c.u;
}
__device__ __forceinline__ half2v u2h(uint32_t u) {
    union { uint32_t u; half2v h; } c; c.u = u; return c.h;
}
__device__ __forceinline__ uint32_t h2u(half2v h) {
    union { half2v h; uint32_t u; } c; c.h = h; return c.u;
}

// ---- pass 0a: x f32 -> f16 into workspace ----
__global__ __launch_bounds__(256)
void cvt_x(const float* __restrict__ x, unsigned short* __restrict__ xb, int n8) {
    int i = blockIdx.x * 256 + threadIdx.x;
    const int stride = gridDim.x * 256;
    for (; i < n8; i += stride) {
        floatx4 a = *(const floatx4*)(x + (size_t)i * 8);
        floatx4 b = *(const floatx4*)(x + (size_t)i * 8 + 4);
        union { short8 v; uint32_t u[4]; } o;
        o.u[0] = pkh(a[0], a[1]);
        o.u[1] = pkh(a[2], a[3]);
        o.u[2] = pkh(b[0], b[1]);
        o.u[3] = pkh(b[2], b[3]);
        *(short8*)(xb + (size_t)i * 8) = o.v;
    }
}

// ---- pass 0b: dequantize W once into tiled f16 image ----
// wb region (nt, t): 8192 B = [kb=4][col=128][k8=8] f16, k = t*32 + kb*8 + k8, n = nt*128 + col.
__global__ __launch_bounds__(256)
void deq_w(const int* __restrict__ qweight, const int* __restrict__ qzeros,
           const float* __restrict__ scales, unsigned short* __restrict__ wb) {
    const int nt = blockIdx.x;          // 0..85
    const int t  = blockIdx.y;          // 0..127 (K-step)
    const int c  = threadIdx.x & 127;   // local col
    const int kh = threadIdx.x >> 7;    // 0/1 -> kb pair
    const int g  = t >> 2;              // group (128 k / 32 k-per-step)
    const int col  = nt * 128 + c;
    const int sh   = ((c & 1) ? 16 : 0) + ((c & 7) >> 1) * 4;   // AWQ inverse order
    const int word = nt * 16 + (c >> 3);

    const uint32_t zw = (uint32_t)qzeros[(size_t)g * NQ_DIM + word];
    const uint32_t zn = ((zw >> sh) & 0xFu) | 0x6400u;          // 1024 + z
    const half2v zt = u2h(zn | (zn << 16));
    const float s = scales[(size_t)g * N_DIM + col];
    half2v st; st[0] = (_Float16)s; st[1] = (_Float16)s;

    const int* qp = qweight + (size_t)(t * 32 + kh * 16) * NQ_DIM + word;
    unsigned short* wt = wb + ((size_t)nt * 128 + t) * 4096;    // halves

#pragma unroll
    for (int h = 0; h < 2; ++h) {                               // kb = kh*2 + h
        union { half8 v; uint32_t u[4]; } o;
#pragma unroll
        for (int p = 0; p < 4; ++p) {
            const uint32_t qa = (uint32_t)qp[(size_t)(h * 8 + 2 * p)     * NQ_DIM];
            const uint32_t qb = (uint32_t)qp[(size_t)(h * 8 + 2 * p + 1) * NQ_DIM];
            uint32_t u = ((qa >> sh) & 0xFu) | (((qb >> sh) & 0xFu) << 16) | 0x64006400u;
            o.u[p] = h2u((u2h(u) - zt) * st);                   // exact int sub, fp16 mul
        }
        *(half8*)(wt + (size_t)(((kh * 2 + h) * 128 + c) * 8)) = o.v;
    }
}

// ---- main GEMM: BM=128 x BN=128, BK=32, 256 thr (4 waves 2Mx2N), all-gl_lds staging ----
// LDS: A buf0 [0,8K), A buf1 [8K,16K) : [kb=4][row=128][8k] f16
//      B buf0 [16K,24K), B buf1 [24K,32K): [kb=4][col=128][8k] f16 (linear, = wb image)
__global__ __launch_bounds__(256, 3)
void awq_gemm6(const unsigned short* __restrict__ xb,
               const unsigned short* __restrict__ wb,
               const float* __restrict__ bias,
               float* __restrict__ out)
{
    __shared__ char lds[32768] __attribute__((aligned(128)));

    const int tid  = threadIdx.x;
    const int lane = tid & 63;
    const int wid  = tid >> 6;

    const int n0 = blockIdx.x * BN;
    const int m0 = blockIdx.y * BM;

    // A staging: wave wid stages kb=wid; rows via lanes (16B = full 8-k slice)
    const unsigned short* agl0 = xb + (size_t)(m0 + lane) * K_DIM + wid * 8;
    const unsigned short* agl1 = xb + (size_t)(m0 + 64 + lane) * K_DIM + wid * 8;
    // B staging: linear copy of the 8KB tile image; per wave 2KB
    const unsigned short* wbp = wb + ((size_t)blockIdx.x * 128) * 4096 + wid * 1024 + lane * 8;

    // fragment read offsets (within-buf)
    const int wm = (wid >> 1) * 64;
    const int wn = (wid & 1) * 64;
    const int lm = lane & 15;
    const int kb_l = lane >> 4;
    const int aoff = kb_l * 2048 + (wm + lm) * 16;       // + i*256
    const int boff = kb_l * 2048 + (wn + lm) * 16;       // + j*256

    floatx4 acc[4][4];
#pragma unroll
    for (int i = 0; i < 4; ++i)
#pragma unroll
        for (int j = 0; j < 4; ++j)
            acc[i][j] = (floatx4){0.f, 0.f, 0.f, 0.f};

    auto stage = [&](int dbuf) {
        const int ab = dbuf * 8192;
        const int bb = 16384 + dbuf * 8192;
        __builtin_amdgcn_global_load_lds(
            (const __attribute__((address_space(1))) void*)agl0,
            (__attribute__((address_space(3))) void*)(&lds[ab + wid * 2048]), 16, 0, 0);
        __builtin_amdgcn_global_load_lds(
            (const __attribute__((address_space(1))) void*)agl1,
            (__attribute__((address_space(3))) void*)(&lds[ab + wid * 2048 + 1024]), 16, 0, 0);
        __builtin_amdgcn_global_load_lds(
            (const __attribute__((address_space(1))) void*)wbp,
            (__attribute__((address_space(3))) void*)(&lds[bb + wid * 2048]), 16, 0, 0);
        __builtin_amdgcn_global_load_lds(
            (const __attribute__((address_space(1))) void*)(wbp + 512),
            (__attribute__((address_space(3))) void*)(&lds[bb + wid * 2048 + 1024]), 16, 0, 0);
        agl0 += BK; agl1 += BK; wbp += 4096;
    };
    auto compute = [&](int dbuf) {
        const int ab = dbuf * 8192;
        const int bb = 16384 + dbuf * 8192;
        half8 af[4], bf[4];
#pragma unroll
        for (int i = 0; i < 4; ++i) af[i] = *(const half8*)&lds[ab + aoff + i * 256];
#pragma unroll
        for (int j = 0; j < 4; ++j) bf[j] = *(const half8*)&lds[bb + boff + j * 256];
#pragma unroll
        for (int i = 0; i < 4; ++i)
#pragma unroll
            for (int j = 0; j < 4; ++j)
                acc[i][j] = __builtin_amdgcn_mfma_f32_16x16x32_f16(af[i], bf[j], acc[i][j], 0, 0, 0);
    };

    // prologue
    stage(0);
    __syncthreads();

    for (int t = 0; t < NSTEPS; t += 2) {
        stage(1);                        // tile t+1
        compute(0);                      // tile t
        __syncthreads();
        if (t + 2 < NSTEPS) stage(0);    // tile t+2
        compute(1);                      // tile t+1
        __syncthreads();
    }

    // epilogue: C/D col = lane&15, row = (lane>>4)*4 + r
    const int colb = n0 + wn + lm;
    const int rowb = m0 + wm + (kb_l << 2);
#pragma unroll
    for (int j = 0; j < 4; ++j) {
        const int col = colb + j * 16;
        const float bias_f = bias[col];
#pragma unroll
        for (int i = 0; i < 4; ++i) {
            const int row = rowb + i * 16;
#pragma unroll
            for (int r = 0; r < 4; ++r) {
                out[(size_t)(row + r) * N_DIM + col] = acc[i][j][r] + bias_f;
            }
        }
    }
}

// ================= R8 fused kernel (fallback when ws too small) =================
template <bool PRECVT>
__global__ __launch_bounds__(256, 3)
void awq_gemm5(const float* __restrict__ xf,
               const unsigned short* __restrict__ xb,
               const int* __restrict__ qweight,
               const int* __restrict__ qzeros,
               const float* __restrict__ scales,
               const float* __restrict__ bias,
               float* __restrict__ out)
{
    __shared__ char lds[32768] __attribute__((aligned(128)));
    const int tid  = threadIdx.x;
    const int lane = tid & 63;
    const int wid  = tid >> 6;
    const int n0 = blockIdx.x * BN;
    const int m0 = blockIdx.y * BM;

    const unsigned short* agl0 = xb + (size_t)(m0 + lane) * K_DIM + wid * 8;
    const unsigned short* agl1 = xb + (size_t)(m0 + 64 + lane) * K_DIM + wid * 8;
    const float* aptr = xf + (size_t)(m0 + (tid >> 1)) * K_DIM + (tid & 1) * 16;
    const int awr = ((tid & 1) * 2) * 2048 + (tid >> 1) * 16;

    const int nq      = tid & 15;
    const int k_local = (tid >> 4) * 2;
    const int kb_w    = k_local >> 3;
    const int k8      = k_local & 7;
    const int nq7     = nq & 7;
    const int* qp0 = qweight + blockIdx.x * 16 + nq + (size_t)k_local * NQ_DIM;
    const int* qp1 = qp0 + NQ_DIM;
    const int* zp  = qzeros + blockIdx.x * 16 + nq;
    const float* sp = scales + n0 + nq * 8;
    int baddr[8];
#pragma unroll
    for (int j = 0; j < 8; ++j)
        baddr[j] = 16384 + (kb_w * 128 + nq * 8 + (j ^ nq7)) * 16 + k8 * 2;

    const int wm = (wid >> 1) * 64;
    const int wn = (wid & 1) * 64;
    const int lm = lane & 15;
    const int kb_l = lane >> 4;
    const int aoff = kb_l * 2048 + (wm + lm) * 16;
    int boff[4];
#pragma unroll
    for (int j = 0; j < 4; ++j) {
        int blk = kb_l * 128 + wn + j * 16 + lm;
        blk ^= (blk >> 3) & 7;
        boff[j] = 16384 + blk * 16;
    }

    floatx4 acc[4][4];
#pragma unroll
    for (int i = 0; i < 4; ++i)
#pragma unroll
        for (int j = 0; j < 4; ++j)
            acc[i][j] = (floatx4){0.f, 0.f, 0.f, 0.f};

    half2v zt[4], st[4];
    uint32_t q0, q1;

    auto stage_a = [&](int abase) {
        if constexpr (PRECVT) {
            __builtin_amdgcn_global_load_lds(
                (const __attribute__((address_space(1))) void*)agl0,
                (__attribute__((address_space(3))) void*)(&lds[abase + wid * 2048]), 16, 0, 0);
            __builtin_amdgcn_global_load_lds(
                (const __attribute__((address_space(1))) void*)agl1,
                (__attribute__((address_space(3))) void*)(&lds[abase + wid * 2048 + 1024]), 16, 0, 0);
            agl0 += BK; agl1 += BK;
        } else {
            floatx4 a0 = *(const floatx4*)(aptr + 0);
            floatx4 a1 = *(const floatx4*)(aptr + 4);
            floatx4 a2 = *(const floatx4*)(aptr + 8);
            floatx4 a3 = *(const floatx4*)(aptr + 12);
            aptr += BK;
            union { short8 v; uint32_t u[4]; } o0, o1;
            o0.u[0] = pkh(a0[0], a0[1]); o0.u[1] = pkh(a0[2], a0[3]);
            o0.u[2] = pkh(a1[0], a1[1]); o0.u[3] = pkh(a1[2], a1[3]);
            o1.u[0] = pkh(a2[0], a2[1]); o1.u[1] = pkh(a2[2], a2[3]);
            o1.u[2] = pkh(a3[0], a3[1]); o1.u[3] = pkh(a3[2], a3[3]);
            *(short8*)&lds[abase + awr]        = o0.v;
            *(short8*)&lds[abase + awr + 2048] = o1.v;
        }
    };
    auto load_q = [&]() {
        q0 = (uint32_t)*qp0; q1 = (uint32_t)*qp1;
        qp0 += (size_t)BK * NQ_DIM; qp1 += (size_t)BK * NQ_DIM;
    };
    auto refresh = [&]() {
        const uint32_t zw = (uint32_t)*zp;
        zp += NQ_DIM;
#pragma unroll
        for (int l = 0; l < 4; ++l) {
            zt[l] = u2h(((zw >> (4 * l)) & 0x000F000Fu) | 0x64006400u);
            float2v s2 = *(const float2v*)(sp + 2 * l);
            half2v sh2; sh2[0] = (_Float16)s2[0]; sh2[1] = (_Float16)s2[1];
            st[l] = sh2;
        }
        sp += N_DIM;
    };
    auto deq_store = [&](int off) {
#pragma unroll
        for (int l = 0; l < 4; ++l) {
            uint32_t t0 = ((q0 >> (4 * l)) & 0x000F000Fu) | 0x64006400u;
            uint32_t t1 = ((q1 >> (4 * l)) & 0x000F000Fu) | 0x64006400u;
            half2v w0 = (u2h(t0) - zt[l]) * st[l];
            half2v w1 = (u2h(t1) - zt[l]) * st[l];
            uint32_t p0 = h2u(w0), p1 = h2u(w1);
            uint32_t de = (p0 & 0xFFFFu) | (p1 << 16);
            uint32_t dd = (p0 >> 16) | (p1 & 0xFFFF0000u);
            *(uint32_t*)&lds[baddr[2 * l]     + off] = de;
            *(uint32_t*)&lds[baddr[2 * l + 1] + off] = dd;
        }
    };
    auto compute = [&](int ab, int bb) {
        half8 af[4], bfr[4];
#pragma unroll
        for (int i = 0; i < 4; ++i) af[i] = *(const half8*)&lds[ab + aoff + i * 256];
#pragma unroll
        for (int j = 0; j < 4; ++j) bfr[j] = *(const half8*)&lds[bb + boff[j] - 16384];
#pragma unroll
        for (int i = 0; i < 4; ++i)
#pragma unroll
            for (int j = 0; j < 4; ++j)
                acc[i][j] = __builtin_amdgcn_mfma_f32_16x16x32_f16(af[i], bfr[j], acc[i][j], 0, 0, 0);
    };

    stage_a(0); load_q(); refresh(); deq_store(0); load_q();
    __syncthreads();

    for (int t = 0; t < NSTEPS; t += 2) {
        stage_a(8192);
        deq_store(8192);
        if (t + 2 < NSTEPS) load_q();
        compute(0, 16384);
        __syncthreads();
        if (t + 2 < NSTEPS) {
            stage_a(0);
            if (((t + 2) & 3) == 0) refresh();
            deq_store(0);
            if (t + 3 < NSTEPS) load_q();
        }
        compute(8192, 24576);
        __syncthreads();
    }

    const int colb = n0 + wn + lm;
    const int rowb = m0 + wm + (kb_l << 2);
#pragma unroll
    for (int j = 0; j < 4; ++j) {
        const int col = colb + j * 16;
        const float bias_f = bias[col];
#pragma unroll
        for (int i = 0; i < 4; ++i) {
            const int row = rowb + i * 16;
#pragma unroll
            for (int r = 0; r < 4; ++r) {
                out[(size_t)(row + r) * N_DIM + col] = acc[i][j][r] + bias_f;
            }
        }
    }
}

extern "C" void kernel_launch(void* const* d_in, const int* in_sizes, int n_in,
                              void* d_out, int out_size, void* d_ws, size_t ws_size,
                              hipStream_t stream) {
    const float* x    = (const float*)d_in[0];
    const int* qw     = (const int*)d_in[1];
    const int* qz     = (const int*)d_in[2];
    const float* sc   = (const float*)d_in[3];
    const float* bi   = (const float*)d_in[4];
    float* out        = (float*)d_out;

    const int M = in_sizes[0] / K_DIM;                       // 8192
    const size_t xb_bytes = (size_t)M * K_DIM * 2;           // 64 MiB
    const size_t wb_bytes = (size_t)K_DIM * N_DIM * 2;       // 86 MiB
    dim3 grid(N_DIM / BN, M / BM);                           // (86, 64)

    if (ws_size >= xb_bytes + wb_bytes) {
        unsigned short* xb = (unsigned short*)d_ws;
        unsigned short* wb = (unsigned short*)((char*)d_ws + xb_bytes);
        const int n8 = (int)((size_t)M * K_DIM / 8);
        cvt_x<<<2048, 256, 0, stream>>>(x, xb, n8);
        deq_w<<<dim3(NT_DIM, NSTEPS), 256, 0, stream>>>(qw, qz, sc, wb);
        awq_gemm6<<<grid, 256, 0, stream>>>(xb, wb, bi, out);
    } else if (ws_size >= xb_bytes) {
        unsigned short* xb = (unsigned short*)d_ws;
        const int n8 = (int)((size_t)M * K_DIM / 8);
        cvt_x<<<2048, 256, 0, stream>>>(x, xb, n8);
        awq_gemm5<true><<<grid, 256, 0, stream>>>(x, xb, qw, qz, sc, bi, out);
    } else {
        awq_gemm5<false><<<grid, 256, 0, stream>>>(x, nullptr, qw, qz, sc, bi, out);
    }
}

// Round 10
// 1026.214 us; speedup vs baseline: 1.1014x; 1.1014x over previous
//
#include <hip/hip_runtime.h>
#include <hip/hip_fp16.h>
#include <stdint.h>

typedef __attribute__((ext_vector_type(8))) _Float16 half8;
typedef __attribute__((ext_vector_type(2))) _Float16 half2v;
typedef __attribute__((ext_vector_type(8))) short short8;
typedef __attribute__((ext_vector_type(4))) float floatx4;
typedef __attribute__((ext_vector_type(2))) float float2v;

#define K_DIM 4096
#define N_DIM 11008
#define NQ_DIM 1376
#define NT_DIM 86
#define BK 32
#define NSTEPS 128
#define BM 128
#define BN 128
#define SUPER_M 16   // m-tiles per super-row (launch-order swizzle)

__device__ __forceinline__ uint32_t pkh(float a, float b) {
    half2v h; h[0] = (_Float16)a; h[1] = (_Float16)b;
    union { half2v h; uint32_t u; } c; c.h = h; return c.u;
}
__device__ __forceinline__ half2v u2h(uint32_t u) {
    union { uint32_t u; half2v h; } c; c.u = u; return c.h;
}
__device__ __forceinline__ uint32_t h2u(half2v h) {
    union { half2v h; uint32_t u; } c; c.h = h; return c.u;
}

// ---- pass 0a: x f32 -> f16 into workspace ----
__global__ __launch_bounds__(256)
void cvt_x(const float* __restrict__ x, unsigned short* __restrict__ xb, int n8) {
    int i = blockIdx.x * 256 + threadIdx.x;
    const int stride = gridDim.x * 256;
    for (; i < n8; i += stride) {
        floatx4 a = *(const floatx4*)(x + (size_t)i * 8);
        floatx4 b = *(const floatx4*)(x + (size_t)i * 8 + 4);
        union { short8 v; uint32_t u[4]; } o;
        o.u[0] = pkh(a[0], a[1]);
        o.u[1] = pkh(a[2], a[3]);
        o.u[2] = pkh(b[0], b[1]);
        o.u[3] = pkh(b[2], b[3]);
        *(short8*)(xb + (size_t)i * 8) = o.v;
    }
}

// ---- pass 0b: dequantize W once into tiled f16 image ----
// wb region (nt, t): 8192 B = [kb=4][col=128][k8=8] f16, k = t*32 + kb*8 + k8, n = nt*128 + col.
__global__ __launch_bounds__(256)
void deq_w(const int* __restrict__ qweight, const int* __restrict__ qzeros,
           const float* __restrict__ scales, unsigned short* __restrict__ wb) {
    const int nt = blockIdx.x;          // 0..85
    const int t  = blockIdx.y;          // 0..127 (K-step)
    const int c  = threadIdx.x & 127;   // local col
    const int kh = threadIdx.x >> 7;    // 0/1 -> kb pair
    const int g  = t >> 2;              // group
    const int col  = nt * 128 + c;
    const int sh   = ((c & 1) ? 16 : 0) + ((c & 7) >> 1) * 4;   // AWQ inverse order
    const int word = nt * 16 + (c >> 3);

    const uint32_t zw = (uint32_t)qzeros[(size_t)g * NQ_DIM + word];
    const uint32_t zn = ((zw >> sh) & 0xFu) | 0x6400u;          // 1024 + z
    const half2v zt = u2h(zn | (zn << 16));
    const float s = scales[(size_t)g * N_DIM + col];
    half2v st; st[0] = (_Float16)s; st[1] = (_Float16)s;

    const int* qp = qweight + (size_t)(t * 32 + kh * 16) * NQ_DIM + word;
    unsigned short* wt = wb + ((size_t)nt * 128 + t) * 4096;

#pragma unroll
    for (int h = 0; h < 2; ++h) {                               // kb = kh*2 + h
        union { half8 v; uint32_t u[4]; } o;
#pragma unroll
        for (int p = 0; p < 4; ++p) {
            const uint32_t qa = (uint32_t)qp[(size_t)(h * 8 + 2 * p)     * NQ_DIM];
            const uint32_t qb = (uint32_t)qp[(size_t)(h * 8 + 2 * p + 1) * NQ_DIM];
            uint32_t u = ((qa >> sh) & 0xFu) | (((qb >> sh) & 0xFu) << 16) | 0x64006400u;
            o.u[p] = h2u((u2h(u) - zt) * st);                   // exact int sub, fp16 mul
        }
        *(half8*)(wt + (size_t)(((kh * 2 + h) * 128 + c) * 8)) = o.v;
    }
}

// ---- main GEMM: BM=128 x BN=128, BK=32, 256 thr (4 waves 2Mx2N), all-gl_lds staging ----
// LDS: A buf0 [0,8K), A buf1 [8K,16K) : [kb=4][row=128][8k] f16
//      B buf0 [16K,24K), B buf1 [24K,32K): [kb=4][col=128][8k] f16 (linear, = wb image)
// Launch-order swizzle: m-fastest within super-rows of SUPER_M m-tiles -> concurrent
// blocks form a compact patch (16 MB xb + ~48 MB wb) that fits L3.
__global__ __launch_bounds__(256, 3)
void awq_gemm6(const unsigned short* __restrict__ xb,
               const unsigned short* __restrict__ wb,
               const float* __restrict__ bias,
               float* __restrict__ out)
{
    __shared__ char lds[32768] __attribute__((aligned(128)));

    const int tid  = threadIdx.x;
    const int lane = tid & 63;
    const int wid  = tid >> 6;

    // ---- super-tile swizzle (M/BM = 64 = 4 * SUPER_M exactly) ----
    const int flat = blockIdx.y * NT_DIM + blockIdx.x;
    const int per_super = NT_DIM * SUPER_M;
    const int s  = flat / per_super;
    const int r  = flat % per_super;
    const int nt = r >> 4;                 // r / SUPER_M
    const int mt = (s << 4) + (r & (SUPER_M - 1));
    const int n0 = nt * BN;
    const int m0 = mt * BM;

    // A staging: wave wid stages kb=wid; rows via lanes (16B = full 8-k slice)
    const unsigned short* agl0 = xb + (size_t)(m0 + lane) * K_DIM + wid * 8;
    const unsigned short* agl1 = xb + (size_t)(m0 + 64 + lane) * K_DIM + wid * 8;
    // B staging: linear copy of the 8KB tile image; per wave 2KB
    const unsigned short* wbp = wb + ((size_t)nt * 128) * 4096 + wid * 1024 + lane * 8;

    // fragment read offsets (within-buf)
    const int wm = (wid >> 1) * 64;
    const int wn = (wid & 1) * 64;
    const int lm = lane & 15;
    const int kb_l = lane >> 4;
    const int aoff = kb_l * 2048 + (wm + lm) * 16;       // + i*256
    const int boff = kb_l * 2048 + (wn + lm) * 16;       // + j*256

    floatx4 acc[4][4];
#pragma unroll
    for (int i = 0; i < 4; ++i)
#pragma unroll
        for (int j = 0; j < 4; ++j)
            acc[i][j] = (floatx4){0.f, 0.f, 0.f, 0.f};

    auto stage = [&](int dbuf) {
        const int ab = dbuf * 8192;
        const int bb = 16384 + dbuf * 8192;
        __builtin_amdgcn_global_load_lds(
            (const __attribute__((address_space(1))) void*)agl0,
            (__attribute__((address_space(3))) void*)(&lds[ab + wid * 2048]), 16, 0, 0);
        __builtin_amdgcn_global_load_lds(
            (const __attribute__((address_space(1))) void*)agl1,
            (__attribute__((address_space(3))) void*)(&lds[ab + wid * 2048 + 1024]), 16, 0, 0);
        __builtin_amdgcn_global_load_lds(
            (const __attribute__((address_space(1))) void*)wbp,
            (__attribute__((address_space(3))) void*)(&lds[bb + wid * 2048]), 16, 0, 0);
        __builtin_amdgcn_global_load_lds(
            (const __attribute__((address_space(1))) void*)(wbp + 512),
            (__attribute__((address_space(3))) void*)(&lds[bb + wid * 2048 + 1024]), 16, 0, 0);
        agl0 += BK; agl1 += BK; wbp += 4096;
    };
    auto compute = [&](int dbuf) {
        const int ab = dbuf * 8192;
        const int bb = 16384 + dbuf * 8192;
        half8 af[4], bf[4];
#pragma unroll
        for (int i = 0; i < 4; ++i) af[i] = *(const half8*)&lds[ab + aoff + i * 256];
#pragma unroll
        for (int j = 0; j < 4; ++j) bf[j] = *(const half8*)&lds[bb + boff + j * 256];
#pragma unroll
        for (int i = 0; i < 4; ++i)
#pragma unroll
            for (int j = 0; j < 4; ++j)
                acc[i][j] = __builtin_amdgcn_mfma_f32_16x16x32_f16(af[i], bf[j], acc[i][j], 0, 0, 0);
    };

    // prologue
    stage(0);
    __syncthreads();

    for (int t = 0; t < NSTEPS; t += 2) {
        stage(1);                        // tile t+1
        compute(0);                      // tile t
        __syncthreads();
        if (t + 2 < NSTEPS) stage(0);    // tile t+2
        compute(1);                      // tile t+1
        __syncthreads();
    }

    // epilogue: C/D col = lane&15, row = (lane>>4)*4 + r ; non-temporal stores
    const int colb = n0 + wn + lm;
    const int rowb = m0 + wm + (kb_l << 2);
#pragma unroll
    for (int j = 0; j < 4; ++j) {
        const int col = colb + j * 16;
        const float bias_f = bias[col];
#pragma unroll
        for (int i = 0; i < 4; ++i) {
            const int row = rowb + i * 16;
#pragma unroll
            for (int r4 = 0; r4 < 4; ++r4) {
                __builtin_nontemporal_store(acc[i][j][r4] + bias_f,
                                            &out[(size_t)(row + r4) * N_DIM + col]);
            }
        }
    }
}

// ================= R8 fused kernel (fallback when ws too small) =================
template <bool PRECVT>
__global__ __launch_bounds__(256, 3)
void awq_gemm5(const float* __restrict__ xf,
               const unsigned short* __restrict__ xb,
               const int* __restrict__ qweight,
               const int* __restrict__ qzeros,
               const float* __restrict__ scales,
               const float* __restrict__ bias,
               float* __restrict__ out)
{
    __shared__ char lds[32768] __attribute__((aligned(128)));
    const int tid  = threadIdx.x;
    const int lane = tid & 63;
    const int wid  = tid >> 6;
    const int n0 = blockIdx.x * BN;
    const int m0 = blockIdx.y * BM;

    const unsigned short* agl0 = xb + (size_t)(m0 + lane) * K_DIM + wid * 8;
    const unsigned short* agl1 = xb + (size_t)(m0 + 64 + lane) * K_DIM + wid * 8;
    const float* aptr = xf + (size_t)(m0 + (tid >> 1)) * K_DIM + (tid & 1) * 16;
    const int awr = ((tid & 1) * 2) * 2048 + (tid >> 1) * 16;

    const int nq      = tid & 15;
    const int k_local = (tid >> 4) * 2;
    const int kb_w    = k_local >> 3;
    const int k8      = k_local & 7;
    const int nq7     = nq & 7;
    const int* qp0 = qweight + blockIdx.x * 16 + nq + (size_t)k_local * NQ_DIM;
    const int* qp1 = qp0 + NQ_DIM;
    const int* zp  = qzeros + blockIdx.x * 16 + nq;
    const float* sp = scales + n0 + nq * 8;
    int baddr[8];
#pragma unroll
    for (int j = 0; j < 8; ++j)
        baddr[j] = 16384 + (kb_w * 128 + nq * 8 + (j ^ nq7)) * 16 + k8 * 2;

    const int wm = (wid >> 1) * 64;
    const int wn = (wid & 1) * 64;
    const int lm = lane & 15;
    const int kb_l = lane >> 4;
    const int aoff = kb_l * 2048 + (wm + lm) * 16;
    int boff[4];
#pragma unroll
    for (int j = 0; j < 4; ++j) {
        int blk = kb_l * 128 + wn + j * 16 + lm;
        blk ^= (blk >> 3) & 7;
        boff[j] = 16384 + blk * 16;
    }

    floatx4 acc[4][4];
#pragma unroll
    for (int i = 0; i < 4; ++i)
#pragma unroll
        for (int j = 0; j < 4; ++j)
            acc[i][j] = (floatx4){0.f, 0.f, 0.f, 0.f};

    half2v zt[4], st[4];
    uint32_t q0, q1;

    auto stage_a = [&](int abase) {
        if constexpr (PRECVT) {
            __builtin_amdgcn_global_load_lds(
                (const __attribute__((address_space(1))) void*)agl0,
                (__attribute__((address_space(3))) void*)(&lds[abase + wid * 2048]), 16, 0, 0);
            __builtin_amdgcn_global_load_lds(
                (const __attribute__((address_space(1))) void*)agl1,
                (__attribute__((address_space(3))) void*)(&lds[abase + wid * 2048 + 1024]), 16, 0, 0);
            agl0 += BK; agl1 += BK;
        } else {
            floatx4 a0 = *(const floatx4*)(aptr + 0);
            floatx4 a1 = *(const floatx4*)(aptr + 4);
            floatx4 a2 = *(const floatx4*)(aptr + 8);
            floatx4 a3 = *(const floatx4*)(aptr + 12);
            aptr += BK;
            union { short8 v; uint32_t u[4]; } o0, o1;
            o0.u[0] = pkh(a0[0], a0[1]); o0.u[1] = pkh(a0[2], a0[3]);
            o0.u[2] = pkh(a1[0], a1[1]); o0.u[3] = pkh(a1[2], a1[3]);
            o1.u[0] = pkh(a2[0], a2[1]); o1.u[1] = pkh(a2[2], a2[3]);
            o1.u[2] = pkh(a3[0], a3[1]); o1.u[3] = pkh(a3[2], a3[3]);
            *(short8*)&lds[abase + awr]        = o0.v;
            *(short8*)&lds[abase + awr + 2048] = o1.v;
        }
    };
    auto load_q = [&]() {
        q0 = (uint32_t)*qp0; q1 = (uint32_t)*qp1;
        qp0 += (size_t)BK * NQ_DIM; qp1 += (size_t)BK * NQ_DIM;
    };
    auto refresh = [&]() {
        const uint32_t zw = (uint32_t)*zp;
        zp += NQ_DIM;
#pragma unroll
        for (int l = 0; l < 4; ++l) {
            zt[l] = u2h(((zw >> (4 * l)) & 0x000F000Fu) | 0x64006400u);
            float2v s2 = *(const float2v*)(sp + 2 * l);
            half2v sh2; sh2[0] = (_Float16)s2[0]; sh2[1] = (_Float16)s2[1];
            st[l] = sh2;
        }
        sp += N_DIM;
    };
    auto deq_store = [&](int off) {
#pragma unroll
        for (int l = 0; l < 4; ++l) {
            uint32_t t0 = ((q0 >> (4 * l)) & 0x000F000Fu) | 0x64006400u;
            uint32_t t1 = ((q1 >> (4 * l)) & 0x000F000Fu) | 0x64006400u;
            half2v w0 = (u2h(t0) - zt[l]) * st[l];
            half2v w1 = (u2h(t1) - zt[l]) * st[l];
            uint32_t p0 = h2u(w0), p1 = h2u(w1);
            uint32_t de = (p0 & 0xFFFFu) | (p1 << 16);
            uint32_t dd = (p0 >> 16) | (p1 & 0xFFFF0000u);
            *(uint32_t*)&lds[baddr[2 * l]     + off] = de;
            *(uint32_t*)&lds[baddr[2 * l + 1] + off] = dd;
        }
    };
    auto compute = [&](int ab, int bb) {
        half8 af[4], bfr[4];
#pragma unroll
        for (int i = 0; i < 4; ++i) af[i] = *(const half8*)&lds[ab + aoff + i * 256];
#pragma unroll
        for (int j = 0; j < 4; ++j) bfr[j] = *(const half8*)&lds[bb + boff[j] - 16384];
#pragma unroll
        for (int i = 0; i < 4; ++i)
#pragma unroll
            for (int j = 0; j < 4; ++j)
                acc[i][j] = __builtin_amdgcn_mfma_f32_16x16x32_f16(af[i], bfr[j], acc[i][j], 0, 0, 0);
    };

    stage_a(0); load_q(); refresh(); deq_store(0); load_q();
    __syncthreads();

    for (int t = 0; t < NSTEPS; t += 2) {
        stage_a(8192);
        deq_store(8192);
        if (t + 2 < NSTEPS) load_q();
        compute(0, 16384);
        __syncthreads();
        if (t + 2 < NSTEPS) {
            stage_a(0);
            if (((t + 2) & 3) == 0) refresh();
            deq_store(0);
            if (t + 3 < NSTEPS) load_q();
        }
        compute(8192, 24576);
        __syncthreads();
    }

    const int colb = n0 + wn + lm;
    const int rowb = m0 + wm + (kb_l << 2);
#pragma unroll
    for (int j = 0; j < 4; ++j) {
        const int col = colb + j * 16;
        const float bias_f = bias[col];
#pragma unroll
        for (int i = 0; i < 4; ++i) {
            const int row = rowb + i * 16;
#pragma unroll
            for (int r4 = 0; r4 < 4; ++r4) {
                out[(size_t)(row + r4) * N_DIM + col] = acc[i][j][r4] + bias_f;
            }
        }
    }
}

extern "C" void kernel_launch(void* const* d_in, const int* in_sizes, int n_in,
                              void* d_out, int out_size, void* d_ws, size_t ws_size,
                              hipStream_t stream) {
    const float* x    = (const float*)d_in[0];
    const int* qw     = (const int*)d_in[1];
    const int* qz     = (const int*)d_in[2];
    const float* sc   = (const float*)d_in[3];
    const float* bi   = (const float*)d_in[4];
    float* out        = (float*)d_out;

    const int M = in_sizes[0] / K_DIM;                       // 8192
    const size_t xb_bytes = (size_t)M * K_DIM * 2;           // 64 MiB
    const size_t wb_bytes = (size_t)K_DIM * N_DIM * 2;       // 86 MiB
    dim3 grid(N_DIM / BN, M / BM);                           // (86, 64)

    if (ws_size >= xb_bytes + wb_bytes) {
        unsigned short* xb = (unsigned short*)d_ws;
        unsigned short* wb = (unsigned short*)((char*)d_ws + xb_bytes);
        const int n8 = (int)((size_t)M * K_DIM / 8);
        cvt_x<<<2048, 256, 0, stream>>>(x, xb, n8);
        deq_w<<<dim3(NT_DIM, NSTEPS), 256, 0, stream>>>(qw, qz, sc, wb);
        awq_gemm6<<<grid, 256, 0, stream>>>(xb, wb, bi, out);
    } else if (ws_size >= xb_bytes) {
        unsigned short* xb = (unsigned short*)d_ws;
        const int n8 = (int)((size_t)M * K_DIM / 8);
        cvt_x<<<2048, 256, 0, stream>>>(x, xb, n8);
        awq_gemm5<true><<<grid, 256, 0, stream>>>(x, xb, qw, qz, sc, bi, out);
    } else {
        awq_gemm5<false><<<grid, 256, 0, stream>>>(x, nullptr, qw, qz, sc, bi, out);
    }
}